// Round 3
// baseline (1506.823 us; speedup 1.0000x reference)
//
#include <hip/hip_runtime.h>
#include <stdint.h>
#include <math.h>

#define NB 4096
#define NT 1024

// Output layout (float32, concatenated in return order):
//   yseq_full: [NB][NT][4]  at offset 0
//   yseq:      [NB][NT][2]  at offset NB*NT*4
//   xseq:      [NB][NT][3]  at offset NB*NT*6

// 16-lane allreduce via shfl_xor butterfly (masks < 16 stay in the 16-group).
__device__ __forceinline__ float xred16(float v) {
  v += __shfl_xor(v, 8);
  v += __shfl_xor(v, 4);
  v += __shfl_xor(v, 2);
  v += __shfl_xor(v, 1);
  return v;
}
__device__ __forceinline__ void xred16_2(float& a, float& b) {
  float ta, tb;
  ta = __shfl_xor(a, 8); tb = __shfl_xor(b, 8); a += ta; b += tb;
  ta = __shfl_xor(a, 4); tb = __shfl_xor(b, 4); a += ta; b += tb;
  ta = __shfl_xor(a, 2); tb = __shfl_xor(b, 2); a += ta; b += tb;
  ta = __shfl_xor(a, 1); tb = __shfl_xor(b, 1); a += ta; b += tb;
}

// ---------------------------------------------------------------------------
// Phase 1: sequential x-recurrence. 16 lanes per chain (one hidden unit of
// r1/r2 per lane), shfl_xor allreduce for the 16-wide dot products.
// Writes x_t (f32) into yseq_full[...,0:3], yseq, xseq.
// ---------------------------------------------------------------------------
__global__ __launch_bounds__(256) void phase1_kernel(
    const float* __restrict__ u, const float* __restrict__ xz0,
    const float* __restrict__ r1W1, const float* __restrict__ r1b1,
    const float* __restrict__ r1W2, const float* __restrict__ r1b2,
    const float* __restrict__ r2W1, const float* __restrict__ r2b1,
    const float* __restrict__ r2W2, const float* __restrict__ r2b2,
    const float* __restrict__ eCW1, const float* __restrict__ eCb1,
    const float* __restrict__ eCW2, const float* __restrict__ eCb2,
    float* __restrict__ out) {
  const int lane = threadIdx.x & 15;
  const int chain = (blockIdx.x << 4) + (threadIdx.x >> 4);

  // per-lane weights (hidden unit = lane)
  const float w1a = r1W1[lane];
  const float w1b = r1b1[lane];
  const float w1c = r1W2[lane];
  const float c1 = r1b2[0];
  const float w2a = r2W1[lane];        // row 0 of (2,16)
  const float w2b = r2W1[16 + lane];   // row 1
  const float w2c = r2b1[lane];
  const float w2d = r2W2[lane];
  const float c2 = r2b2[0];

  const float* xzr = xz0 + chain * 18;
  float x0 = xzr[0];
  float x1 = xzr[1];

  // Cc0 = eC(z0): lane handles hidden units lane and lane+16
  float hA = eCb1[lane], hB = eCb1[lane + 16];
#pragma unroll
  for (int i = 0; i < 15; ++i) {
    const float z = xzr[3 + i];
    hA = __builtin_fmaf(z, eCW1[i * 32 + lane], hA);
    hB = __builtin_fmaf(z, eCW1[i * 32 + lane + 16], hB);
  }
  float p = tanhf(hA) * eCW2[lane] + tanhf(hB) * eCW2[lane + 16];
  float x2 = xred16(p) + eCb2[0];

  const float* urow = u + (size_t)chain * NT;
  float* yf = out + (size_t)chain * NT * 4;
  float* ys = out + (size_t)NB * NT * 4 + (size_t)chain * NT * 2;
  float* xs = out + (size_t)NB * NT * 6 + (size_t)chain * NT * 3;

  float a_u;  // (u/6 + 1/6), set once per step
  // fxu with normalization constants folded:
  //   k0 = a_u - 0.1*s0 - n1
  //   k1 = -0.1*s1 - 0.2 + 1.5*n1 - 3*n2
  //   k2 = -0.1*s2 - 0.2 + n2
  auto fxu = [&](float s0, float s1, float s2, float& k0, float& k1,
                 float& k2) {
    float p1 = tanhf(__builtin_fmaf(s0, w1a, w1b)) * w1c;
    float p2 =
        tanhf(__builtin_fmaf(s1, w2a, __builtin_fmaf(s2, w2b, w2c))) * w2d;
    xred16_2(p1, p2);
    const float n1 = p1 + c1;
    const float n2 = p2 + c2;
    k0 = __builtin_fmaf(-0.1f, s0, a_u) - n1;
    float t1 = __builtin_fmaf(-0.1f, s1, -0.2f);
    t1 = __builtin_fmaf(1.5f, n1, t1);
    k1 = __builtin_fmaf(-3.0f, n2, t1);
    k2 = __builtin_fmaf(-0.1f, s2, -0.2f) + n2;
  };

  float4 ucur = *(const float4*)urow;
  for (int t4 = 0; t4 < NT; t4 += 4) {
    const int tn = (t4 + 4 < NT) ? (t4 + 4) : (NT - 4);
    const float4 unext = *(const float4*)(urow + tn);  // prefetch next group
    float us[4] = {ucur.x, ucur.y, ucur.z, ucur.w};
#pragma unroll
    for (int e = 0; e < 4; ++e) {
      const int t = t4 + e;
      if (lane == 0) {
        *(float2*)(yf + t * 4) = make_float2(x0, x1);  // yseq_full[...,0:2]
        yf[t * 4 + 2] = x2;                            // yseq_full[...,2]
        *(float2*)(ys + t * 2) = make_float2(x0, x1);  // yseq
        xs[t * 3 + 0] = x0;                            // xseq
        xs[t * 3 + 1] = x1;
        xs[t * 3 + 2] = x2;
      }
      const float uu = us[e];
      a_u = __builtin_fmaf(uu, 1.0f / 6.0f, 1.0f / 6.0f);
      float k10, k11, k12, k20, k21, k22, k30, k31, k32, k40, k41, k42;
      fxu(x0, x1, x2, k10, k11, k12);
      fxu(__builtin_fmaf(0.5f, k10, x0), __builtin_fmaf(0.5f, k11, x1),
          __builtin_fmaf(0.5f, k12, x2), k20, k21, k22);
      fxu(__builtin_fmaf(0.5f, k20, x0), __builtin_fmaf(0.5f, k21, x1),
          __builtin_fmaf(0.5f, k22, x2), k30, k31, k32);
      fxu(x0 + k30, x1 + k31, x2 + k32, k40, k41, k42);
      x0 += (k10 + 2.0f * (k20 + k30) + k40) * (1.0f / 6.0f);
      x1 += (k11 + 2.0f * (k21 + k31) + k41) * (1.0f / 6.0f);
      x2 += (k12 + 2.0f * (k22 + k32) + k42) * (1.0f / 6.0f);
    }
    ucur = unext;
  }
}

// ---------------------------------------------------------------------------
// Phase 2: CcNN = eC(z_t) for all (b,t), fully parallel. One block per batch
// row; each thread does 4 consecutive t (shared y/u window). Weights in LDS,
// row-major [j][16] with bias in slot 15 -> 4x ds_read_b128 per hidden unit.
// y history read (exact f32) from the yseq region phase 1 wrote.
// ---------------------------------------------------------------------------
__global__ __launch_bounds__(256) void phase2_kernel(
    const float* __restrict__ u, const float* __restrict__ xz0,
    const float* __restrict__ eCW1, const float* __restrict__ eCb1,
    const float* __restrict__ eCW2, const float* __restrict__ eCb2,
    float* __restrict__ out) {
  __shared__ float lw[32][16];
  __shared__ float lw2[32];
  const int tid = threadIdx.x;
  if (tid < 32) {
#pragma unroll
    for (int i = 0; i < 15; ++i) lw[tid][i] = eCW1[i * 32 + tid];
    lw[tid][15] = eCb1[tid];
    lw2[tid] = eCW2[tid];
  }
  __syncthreads();

  const int b = blockIdx.x;
  const int t0 = tid << 2;
  const float2* ysrow =
      (const float2*)(out + (size_t)NB * NT * 4) + (size_t)b * NT;
  const float* urow = u + (size_t)b * NT;
  const float* xzr = xz0 + b * 18;

  // window: times t' = t0-5 .. t0+2; t' < 0 comes from z0 (entry t'+5)
  float yw[16], uw[8];
#pragma unroll
  for (int idx = 0; idx < 8; ++idx) {
    const int tp = t0 - 5 + idx;
    float a, c, uu;
    if (tp >= 0) {
      const float2 h = ysrow[tp];
      a = h.x;
      c = h.y;
      uu = urow[tp];
    } else {
      a = xzr[3 + 2 * (tp + 5)];
      c = xzr[4 + 2 * (tp + 5)];
      uu = xzr[13 + (tp + 5)];
    }
    yw[2 * idx] = a;
    yw[2 * idx + 1] = c;
    uw[idx] = uu;
  }

  float acc[4] = {0.f, 0.f, 0.f, 0.f};
  for (int j = 0; j < 32; ++j) {
    const float4 wa = ((const float4*)lw[j])[0];
    const float4 wb = ((const float4*)lw[j])[1];
    const float4 wc = ((const float4*)lw[j])[2];
    const float4 wd = ((const float4*)lw[j])[3];  // .w = bias
    const float w2 = lw2[j];
#pragma unroll
    for (int e = 0; e < 4; ++e) {
      float h = wd.w;
      h = __builtin_fmaf(yw[2 * e + 0], wa.x, h);
      h = __builtin_fmaf(yw[2 * e + 1], wa.y, h);
      h = __builtin_fmaf(yw[2 * e + 2], wa.z, h);
      h = __builtin_fmaf(yw[2 * e + 3], wa.w, h);
      h = __builtin_fmaf(yw[2 * e + 4], wb.x, h);
      h = __builtin_fmaf(yw[2 * e + 5], wb.y, h);
      h = __builtin_fmaf(yw[2 * e + 6], wb.z, h);
      h = __builtin_fmaf(yw[2 * e + 7], wb.w, h);
      h = __builtin_fmaf(yw[2 * e + 8], wc.x, h);
      h = __builtin_fmaf(yw[2 * e + 9], wc.y, h);
      h = __builtin_fmaf(uw[e + 0], wc.z, h);
      h = __builtin_fmaf(uw[e + 1], wc.w, h);
      h = __builtin_fmaf(uw[e + 2], wd.x, h);
      h = __builtin_fmaf(uw[e + 3], wd.y, h);
      h = __builtin_fmaf(uw[e + 4], wd.z, h);
      acc[e] = __builtin_fmaf(tanhf(h), w2, acc[e]);
    }
  }
  const float b2v = eCb2[0];
  float* yfrow = out + (size_t)b * NT * 4;
#pragma unroll
  for (int e = 0; e < 4; ++e) {
    yfrow[(t0 + e) * 4 + 3] = acc[e] + b2v;
  }
}

extern "C" void kernel_launch(void* const* d_in, const int* in_sizes, int n_in,
                              void* d_out, int out_size, void* d_ws,
                              size_t ws_size, hipStream_t stream) {
  const float* u = (const float*)d_in[0];
  const float* xz0 = (const float*)d_in[1];
  const float* r1W1 = (const float*)d_in[2];
  const float* r1b1 = (const float*)d_in[3];
  const float* r1W2 = (const float*)d_in[4];
  const float* r1b2 = (const float*)d_in[5];
  const float* r2W1 = (const float*)d_in[6];
  const float* r2b1 = (const float*)d_in[7];
  const float* r2W2 = (const float*)d_in[8];
  const float* r2b2 = (const float*)d_in[9];
  const float* eCW1 = (const float*)d_in[10];
  const float* eCb1 = (const float*)d_in[11];
  const float* eCW2 = (const float*)d_in[12];
  const float* eCb2 = (const float*)d_in[13];
  float* out = (float*)d_out;

  hipLaunchKernelGGL(phase1_kernel, dim3(NB / 16), dim3(256), 0, stream, u,
                     xz0, r1W1, r1b1, r1W2, r1b2, r2W1, r2b1, r2W2, r2b2, eCW1,
                     eCb1, eCW2, eCb2, out);
  hipLaunchKernelGGL(phase2_kernel, dim3(NB), dim3(256), 0, stream, u, xz0,
                     eCW1, eCb1, eCW2, eCb2, out);
}

// Round 4
// 704.097 us; speedup vs baseline: 2.1401x; 2.1401x over previous
//
#include <hip/hip_runtime.h>
#include <stdint.h>
#include <math.h>

#define NB 4096
#define NT 1024

// Output layout (float32, concatenated in return order):
//   yseq_full: [NB][NT][4]  at offset 0
//   yseq:      [NB][NT][2]  at offset NB*NT*4
//   xseq:      [NB][NT][3]  at offset NB*NT*6

#if __has_builtin(__builtin_amdgcn_exp2f)
#define EXP2F __builtin_amdgcn_exp2f
#else
#define EXP2F exp2f
#endif
#if __has_builtin(__builtin_amdgcn_rcpf)
#define RCPF __builtin_amdgcn_rcpf
#else
#define RCPF(x) (1.0f / (x))
#endif

// tanh(y) = 1 - 2/(1+exp2(y*2*log2(e))); branch-free, saturates at +-1.
// ~30 cyc dependent chain vs ~100+ for libm tanhf. Numerics vetted: rounds
// 1-2 showed bf16-identical trajectories vs tanhf.
__device__ __forceinline__ float fast_tanh(float y) {
  float e = EXP2F(y * 2.885390081777927f);
  float r = RCPF(e + 1.0f);
  return __builtin_fmaf(-2.0f, r, 1.0f);
}

// DPP row_ror:N within 16-lane rows — full-rate VALU cross-lane, no LDS.
template <int CTRL>
__device__ __forceinline__ float dppmov(float x) {
  return __int_as_float(
      __builtin_amdgcn_update_dpp(0, __float_as_int(x), CTRL, 0xF, 0xF, true));
}

// rotate-allreduce: after ror 8,4,2,1 every lane of the 16-row holds the sum.
__device__ __forceinline__ void rowred2(float& a, float& b) {
  a += dppmov<0x128>(a); b += dppmov<0x128>(b);  // row_ror:8
  a += dppmov<0x124>(a); b += dppmov<0x124>(b);  // row_ror:4
  a += dppmov<0x122>(a); b += dppmov<0x122>(b);  // row_ror:2
  a += dppmov<0x121>(a); b += dppmov<0x121>(b);  // row_ror:1
}
__device__ __forceinline__ float rowred1(float a) {
  a += dppmov<0x128>(a);
  a += dppmov<0x124>(a);
  a += dppmov<0x122>(a);
  a += dppmov<0x121>(a);
  return a;
}

// ---------------------------------------------------------------------------
// Phase 1: sequential x-recurrence. 16 lanes per chain (one hidden unit of
// r1/r2 per lane), DPP rotate-allreduce for the 16-wide dot products.
// Latency-bound at 1 wave/SIMD: everything on the chain is minimized.
// ---------------------------------------------------------------------------
__global__ __launch_bounds__(256) void phase1_kernel(
    const float* __restrict__ u, const float* __restrict__ xz0,
    const float* __restrict__ r1W1, const float* __restrict__ r1b1,
    const float* __restrict__ r1W2, const float* __restrict__ r1b2,
    const float* __restrict__ r2W1, const float* __restrict__ r2b1,
    const float* __restrict__ r2W2, const float* __restrict__ r2b2,
    const float* __restrict__ eCW1, const float* __restrict__ eCb1,
    const float* __restrict__ eCW2, const float* __restrict__ eCb2,
    float* __restrict__ out) {
  const int lane = threadIdx.x & 15;
  const int chain = (blockIdx.x << 4) + (threadIdx.x >> 4);

  // per-lane weights (hidden unit = lane)
  const float w1a = r1W1[lane];
  const float w1b = r1b1[lane];
  const float w1c = r1W2[lane];
  const float c1 = r1b2[0];
  const float w2a = r2W1[lane];        // row 0 of (2,16)
  const float w2b = r2W1[16 + lane];   // row 1
  const float w2c = r2b1[lane];
  const float w2d = r2W2[lane];
  const float c2 = r2b2[0];

  const float* xzr = xz0 + chain * 18;
  float x0 = xzr[0];
  float x1 = xzr[1];

  // Cc0 = eC(z0): lane handles hidden units lane and lane+16
  float hA = eCb1[lane], hB = eCb1[lane + 16];
#pragma unroll
  for (int i = 0; i < 15; ++i) {
    const float z = xzr[3 + i];
    hA = __builtin_fmaf(z, eCW1[i * 32 + lane], hA);
    hB = __builtin_fmaf(z, eCW1[i * 32 + lane + 16], hB);
  }
  float p = fast_tanh(hA) * eCW2[lane] + fast_tanh(hB) * eCW2[lane + 16];
  float x2 = rowred1(p) + eCb2[0];

  const float* urow = u + (size_t)chain * NT;
  float* yf = out + (size_t)chain * NT * 4;
  float* ys = out + (size_t)NB * NT * 4 + (size_t)chain * NT * 2;
  float* xs = out + (size_t)NB * NT * 6 + (size_t)chain * NT * 3;

  float a_u;  // (u/6 + 1/6), set once per step
  // fxu with normalization constants folded:
  //   k0 = a_u - 0.1*s0 - n1
  //   k1 = -0.1*s1 - 0.2 + 1.5*n1 - 3*n2
  //   k2 = -0.1*s2 - 0.2 + n2
  auto fxu = [&](float s0, float s1, float s2, float& k0, float& k1,
                 float& k2) {
    float p1 = fast_tanh(__builtin_fmaf(s0, w1a, w1b)) * w1c;
    float p2 =
        fast_tanh(__builtin_fmaf(s1, w2a, __builtin_fmaf(s2, w2b, w2c))) * w2d;
    rowred2(p1, p2);
    const float n1 = p1 + c1;
    const float n2 = p2 + c2;
    k0 = __builtin_fmaf(-0.1f, s0, a_u) - n1;
    float t1 = __builtin_fmaf(-0.1f, s1, -0.2f);
    t1 = __builtin_fmaf(1.5f, n1, t1);
    k1 = __builtin_fmaf(-3.0f, n2, t1);
    k2 = __builtin_fmaf(-0.1f, s2, -0.2f) + n2;
  };

  float4 ucur = *(const float4*)urow;
  for (int t4 = 0; t4 < NT; t4 += 4) {
    const int tn = (t4 + 4 < NT) ? (t4 + 4) : (NT - 4);
    const float4 unext = *(const float4*)(urow + tn);  // prefetch next group
    float us[4] = {ucur.x, ucur.y, ucur.z, ucur.w};
#pragma unroll
    for (int e = 0; e < 4; ++e) {
      const int t = t4 + e;
      if (lane == 0) {
        *(float2*)(yf + t * 4) = make_float2(x0, x1);  // yseq_full[...,0:2]
        yf[t * 4 + 2] = x2;                            // yseq_full[...,2]
        *(float2*)(ys + t * 2) = make_float2(x0, x1);  // yseq
        xs[t * 3 + 0] = x0;                            // xseq
        xs[t * 3 + 1] = x1;
        xs[t * 3 + 2] = x2;
      }
      const float uu = us[e];
      a_u = __builtin_fmaf(uu, 1.0f / 6.0f, 1.0f / 6.0f);
      float k10, k11, k12, k20, k21, k22, k30, k31, k32, k40, k41, k42;
      fxu(x0, x1, x2, k10, k11, k12);
      fxu(__builtin_fmaf(0.5f, k10, x0), __builtin_fmaf(0.5f, k11, x1),
          __builtin_fmaf(0.5f, k12, x2), k20, k21, k22);
      fxu(__builtin_fmaf(0.5f, k20, x0), __builtin_fmaf(0.5f, k21, x1),
          __builtin_fmaf(0.5f, k22, x2), k30, k31, k32);
      fxu(x0 + k30, x1 + k31, x2 + k32, k40, k41, k42);
      x0 += (k10 + 2.0f * (k20 + k30) + k40) * (1.0f / 6.0f);
      x1 += (k11 + 2.0f * (k21 + k31) + k41) * (1.0f / 6.0f);
      x2 += (k12 + 2.0f * (k22 + k32) + k42) * (1.0f / 6.0f);
    }
    ucur = unext;
  }
}

// ---------------------------------------------------------------------------
// Phase 2: CcNN = eC(z_t) for all (b,t), fully parallel. One block per batch
// row; each thread does 4 consecutive t (shared y/u window). Weights in LDS,
// row-major [j][16] with bias in slot 15 -> 4x ds_read_b128 per hidden unit.
// y history read (exact f32) from the yseq region phase 1 wrote.
// ---------------------------------------------------------------------------
__global__ __launch_bounds__(256) void phase2_kernel(
    const float* __restrict__ u, const float* __restrict__ xz0,
    const float* __restrict__ eCW1, const float* __restrict__ eCb1,
    const float* __restrict__ eCW2, const float* __restrict__ eCb2,
    float* __restrict__ out) {
  __shared__ float lw[32][16];
  __shared__ float lw2[32];
  const int tid = threadIdx.x;
  if (tid < 32) {
#pragma unroll
    for (int i = 0; i < 15; ++i) lw[tid][i] = eCW1[i * 32 + tid];
    lw[tid][15] = eCb1[tid];
    lw2[tid] = eCW2[tid];
  }
  __syncthreads();

  const int b = blockIdx.x;
  const int t0 = tid << 2;
  const float2* ysrow =
      (const float2*)(out + (size_t)NB * NT * 4) + (size_t)b * NT;
  const float* urow = u + (size_t)b * NT;
  const float* xzr = xz0 + b * 18;

  // window: times t' = t0-5 .. t0+2; t' < 0 comes from z0 (entry t'+5)
  float yw[16], uw[8];
#pragma unroll
  for (int idx = 0; idx < 8; ++idx) {
    const int tp = t0 - 5 + idx;
    float a, c, uu;
    if (tp >= 0) {
      const float2 h = ysrow[tp];
      a = h.x;
      c = h.y;
      uu = urow[tp];
    } else {
      a = xzr[3 + 2 * (tp + 5)];
      c = xzr[4 + 2 * (tp + 5)];
      uu = xzr[13 + (tp + 5)];
    }
    yw[2 * idx] = a;
    yw[2 * idx + 1] = c;
    uw[idx] = uu;
  }

  float acc[4] = {0.f, 0.f, 0.f, 0.f};
  for (int j = 0; j < 32; ++j) {
    const float4 wa = ((const float4*)lw[j])[0];
    const float4 wb = ((const float4*)lw[j])[1];
    const float4 wc = ((const float4*)lw[j])[2];
    const float4 wd = ((const float4*)lw[j])[3];  // .w = bias
    const float w2 = lw2[j];
#pragma unroll
    for (int e = 0; e < 4; ++e) {
      float h = wd.w;
      h = __builtin_fmaf(yw[2 * e + 0], wa.x, h);
      h = __builtin_fmaf(yw[2 * e + 1], wa.y, h);
      h = __builtin_fmaf(yw[2 * e + 2], wa.z, h);
      h = __builtin_fmaf(yw[2 * e + 3], wa.w, h);
      h = __builtin_fmaf(yw[2 * e + 4], wb.x, h);
      h = __builtin_fmaf(yw[2 * e + 5], wb.y, h);
      h = __builtin_fmaf(yw[2 * e + 6], wb.z, h);
      h = __builtin_fmaf(yw[2 * e + 7], wb.w, h);
      h = __builtin_fmaf(yw[2 * e + 8], wc.x, h);
      h = __builtin_fmaf(yw[2 * e + 9], wc.y, h);
      h = __builtin_fmaf(uw[e + 0], wc.z, h);
      h = __builtin_fmaf(uw[e + 1], wc.w, h);
      h = __builtin_fmaf(uw[e + 2], wd.x, h);
      h = __builtin_fmaf(uw[e + 3], wd.y, h);
      h = __builtin_fmaf(uw[e + 4], wd.z, h);
      acc[e] = __builtin_fmaf(fast_tanh(h), w2, acc[e]);
    }
  }
  const float b2v = eCb2[0];
  float* yfrow = out + (size_t)b * NT * 4;
#pragma unroll
  for (int e = 0; e < 4; ++e) {
    yfrow[(t0 + e) * 4 + 3] = acc[e] + b2v;
  }
}

extern "C" void kernel_launch(void* const* d_in, const int* in_sizes, int n_in,
                              void* d_out, int out_size, void* d_ws,
                              size_t ws_size, hipStream_t stream) {
  const float* u = (const float*)d_in[0];
  const float* xz0 = (const float*)d_in[1];
  const float* r1W1 = (const float*)d_in[2];
  const float* r1b1 = (const float*)d_in[3];
  const float* r1W2 = (const float*)d_in[4];
  const float* r1b2 = (const float*)d_in[5];
  const float* r2W1 = (const float*)d_in[6];
  const float* r2b1 = (const float*)d_in[7];
  const float* r2W2 = (const float*)d_in[8];
  const float* r2b2 = (const float*)d_in[9];
  const float* eCW1 = (const float*)d_in[10];
  const float* eCb1 = (const float*)d_in[11];
  const float* eCW2 = (const float*)d_in[12];
  const float* eCb2 = (const float*)d_in[13];
  float* out = (float*)d_out;

  hipLaunchKernelGGL(phase1_kernel, dim3(NB / 16), dim3(256), 0, stream, u,
                     xz0, r1W1, r1b1, r1W2, r1b2, r2W1, r2b1, r2W2, r2b2, eCW1,
                     eCb1, eCW2, eCb2, out);
  hipLaunchKernelGGL(phase2_kernel, dim3(NB), dim3(256), 0, stream, u, xz0,
                     eCW1, eCb1, eCW2, eCb2, out);
}